// Round 4
// baseline (528.664 us; speedup 1.0000x reference)
//
#include <hip/hip_runtime.h>
#include <math.h>

// NeRF renderer: 4096 rays, 128 coarse + 128 fine samples, tiny MLP field.
// One wave (64 lanes) per ray, ONE sample per lane per MLP batch.
// Block = 256 threads = 4 rays. Weights staged in LDS once per block; W2
// reads are wave-uniform broadcasts (conflict-free).
//
// IMPORTANT (R2/R3 lesson): do NOT pass a min-waves arg to __launch_bounds__.
// (256,2) made the backend cap VGPRs at 128 -> h1[64] partially spilled to
// scratch -> 275..520 MB of HBM traffic. Plain (256) gives ~188 VGPRs, no
// spill (R1: 0.47 MB HBM total).

#define BOUNDF 2.0f

struct RayLds {
    float zc[128];        // coarse z
    float zf[128];        // fine z (sorted by construction)
    float sgc[128];       // coarse sigma
    float sgf[128];       // fine sigma
    float rgbc[128][3];
    float rgbf[128][3];
    float cdf[128];       // 127 used
    float scr[128];       // alphas -> weights scratch
    unsigned short perm[256];
};

__device__ __forceinline__ float sigmoidf(float x) { return 1.0f / (1.0f + __expf(-x)); }

__device__ __forceinline__ float scan_incl_mul(float p, int lane) {
#pragma unroll
    for (int off = 1; off < 64; off <<= 1) {
        float t = __shfl_up(p, off, 64);
        if (lane >= off) p *= t;
    }
    return p;
}

__device__ __forceinline__ float scan_incl_add(float p, int lane) {
#pragma unroll
    for (int off = 1; off < 64; off <<= 1) {
        float t = __shfl_up(p, off, 64);
        if (lane >= off) p += t;
    }
    return p;
}

// MLP field eval for ONE point per lane. Weights in LDS:
//   sW1t[j] = {W1[0][j], W1[1][j], W1[2][j], b1[j]}
//   sW2t row j (stride 72): [0..63]=W2[:,j], [64..67]={Wsig[j],Wrgb[j][0..2]}, [68]=b2[j]
__device__ __forceinline__ void eval_field1(
    float px, float py, float pz,
    const float4* __restrict__ sW1t, const float* __restrict__ sW2t,
    float base_r, float base_g, float base_b,
    float& sg, float& r, float& g, float& b)
{
    float h1[64];
#pragma unroll
    for (int j = 0; j < 64; ++j) {
        float4 w = sW1t[j];
        h1[j] = fmaxf(fmaf(px, w.x, fmaf(py, w.y, fmaf(pz, w.z, w.w))), 0.0f);
    }
    float as = 0.f, c0 = 0.f, c1 = 0.f, c2 = 0.f;
#pragma unroll 2
    for (int j = 0; j < 64; ++j) {
        const float* row = sW2t + j * 72;
        // 4 independent accumulator chains to break FMA dependency latency
        float accA = row[68];   // b2[j]
        float accB = 0.f, accC = 0.f, accD = 0.f;
#pragma unroll
        for (int i = 0; i < 64; i += 16) {
            float4 wA = *(const float4*)(row + i + 0);
            float4 wB = *(const float4*)(row + i + 4);
            float4 wC = *(const float4*)(row + i + 8);
            float4 wD = *(const float4*)(row + i + 12);
            accA = fmaf(h1[i + 0], wA.x, accA);
            accA = fmaf(h1[i + 1], wA.y, accA);
            accA = fmaf(h1[i + 2], wA.z, accA);
            accA = fmaf(h1[i + 3], wA.w, accA);
            accB = fmaf(h1[i + 4], wB.x, accB);
            accB = fmaf(h1[i + 5], wB.y, accB);
            accB = fmaf(h1[i + 6], wB.z, accB);
            accB = fmaf(h1[i + 7], wB.w, accB);
            accC = fmaf(h1[i + 8], wC.x, accC);
            accC = fmaf(h1[i + 9], wC.y, accC);
            accC = fmaf(h1[i + 10], wC.z, accC);
            accC = fmaf(h1[i + 11], wC.w, accC);
            accD = fmaf(h1[i + 12], wD.x, accD);
            accD = fmaf(h1[i + 13], wD.y, accD);
            accD = fmaf(h1[i + 14], wD.z, accD);
            accD = fmaf(h1[i + 15], wD.w, accD);
        }
        float h2 = fmaxf((accA + accB) + (accC + accD), 0.0f);
        float4 hd = *(const float4*)(row + 64);   // Wsig, Wrgb0, Wrgb1, Wrgb2
        as = fmaf(h2, hd.x, as);
        c0 = fmaf(h2, hd.y, c0);
        c1 = fmaf(h2, hd.z, c1);
        c2 = fmaf(h2, hd.w, c2);
    }
    sg = fmaxf(as, 0.0f) + log1pf(__expf(-fabsf(as)));   // stable softplus
    r = sigmoidf(c0 + base_r);
    g = sigmoidf(c1 + base_g);
    b = sigmoidf(c2 + base_b);
}

__global__ __launch_bounds__(256)
void nerf_kernel(const float* __restrict__ rays_o, const float* __restrict__ rays_d,
                 const float* __restrict__ W1, const float* __restrict__ b1,
                 const float* __restrict__ W2, const float* __restrict__ b2,
                 const float* __restrict__ Wsig, const float* __restrict__ Wrgb,
                 const float* __restrict__ brgb,
                 float* __restrict__ out_depth, float* __restrict__ out_img,
                 int nRays)
{
    __shared__ __align__(16) float4 sW1t[64];
    __shared__ __align__(16) float sW2t[64 * 72];
    __shared__ RayLds rl[4];

    const int tid  = threadIdx.x;
    const int lane = tid & 63;
    const int wv   = tid >> 6;

    // --- stage weights (whole block) ---
    if (tid < 64) {
        sW1t[tid] = make_float4(W1[tid], W1[64 + tid], W1[128 + tid], b1[tid]);
        sW2t[tid * 72 + 64] = Wsig[tid];
        sW2t[tid * 72 + 65] = Wrgb[tid * 3 + 0];
        sW2t[tid * 72 + 66] = Wrgb[tid * 3 + 1];
        sW2t[tid * 72 + 67] = Wrgb[tid * 3 + 2];
        sW2t[tid * 72 + 68] = b2[tid];
    }
    for (int idx = tid; idx < 4096; idx += 256) {
        int i = idx >> 6, j = idx & 63;
        sW2t[j * 72 + i] = W2[i * 64 + j];   // transposed: row j = column j of W2
    }
    __syncthreads();

    int ray = blockIdx.x * 4 + wv;
    bool valid = ray < nRays;
    int rayc = valid ? ray : (nRays - 1);
    RayLds& R = rl[wv];

    const float ox = rays_o[rayc * 3 + 0], oy = rays_o[rayc * 3 + 1], oz = rays_o[rayc * 3 + 2];
    const float dx = rays_d[rayc * 3 + 0], dy = rays_d[rayc * 3 + 1], dzv = rays_d[rayc * 3 + 2];

    // --- near/far vs cube [-2,2]^3 ---
    float t0x = (-BOUNDF - ox) / (dx + 1e-15f), t1x = (BOUNDF - ox) / (dx + 1e-15f);
    float t0y = (-BOUNDF - oy) / (dy + 1e-15f), t1y = (BOUNDF - oy) / (dy + 1e-15f);
    float t0z = (-BOUNDF - oz) / (dzv + 1e-15f), t1z = (BOUNDF - oz) / (dzv + 1e-15f);
    float nearv = fmaxf(fminf(t0x, t1x), fmaxf(fminf(t0y, t1y), fminf(t0z, t1z)));
    float farv  = fminf(fmaxf(t0x, t1x), fminf(fmaxf(t0y, t1y), fmaxf(t0z, t1z)));
    if (farv < nearv) { nearv = 1e9f; farv = 1e9f; }
    nearv = fmaxf(nearv, 0.05f);
    const float span = farv - nearv;
    const float dzc = span * (1.0f / 127.0f);
    const float sample_dist = span * (1.0f / 128.0f);

    // per-ray rgb bias: brgb + dirs @ Wrgb[64:67]
    const float base_r = brgb[0] + dx * Wrgb[64 * 3 + 0] + dy * Wrgb[65 * 3 + 0] + dzv * Wrgb[66 * 3 + 0];
    const float base_g = brgb[1] + dx * Wrgb[64 * 3 + 1] + dy * Wrgb[65 * 3 + 1] + dzv * Wrgb[66 * 3 + 1];
    const float base_b = brgb[2] + dx * Wrgb[64 * 3 + 2] + dy * Wrgb[65 * 3 + 2] + dzv * Wrgb[66 * 3 + 2];

    // --- coarse eval: 2 batches, one sample per lane ---
#pragma unroll 1
    for (int bt = 0; bt < 2; ++bt) {
        int s = bt * 64 + lane;
        float z = fmaf(span, (float)s * (1.0f / 127.0f), nearv);
        R.zc[s] = z;
        float px = fminf(fmaxf(fmaf(dx, z, ox), -BOUNDF), BOUNDF);
        float py = fminf(fmaxf(fmaf(dy, z, oy), -BOUNDF), BOUNDF);
        float pz = fminf(fmaxf(fmaf(dzv, z, oz), -BOUNDF), BOUNDF);
        float sg, cr, cg, cb;
        eval_field1(px, py, pz, sW1t, sW2t, base_r, base_g, base_b, sg, cr, cg, cb);
        R.sgc[s] = sg;
        R.rgbc[s][0] = cr; R.rgbc[s][1] = cg; R.rgbc[s][2] = cb;
    }

    // --- coarse alphas (deltas from actual z, matching reference) ---
#pragma unroll 1
    for (int bt = 0; bt < 2; ++bt) {
        int s = bt * 64 + lane;
        float delta = (s < 127) ? (R.zc[s + 1] - R.zc[s]) : sample_dist;
        R.scr[s] = 1.0f - __expf(-delta * R.sgc[s]);
    }

    // --- wave-parallel cumprod: weights for elements 2l, 2l+1 ---
    {
        float aa = R.scr[2 * lane], ab = R.scr[2 * lane + 1];
        float ma = 1.0f - aa + 1e-15f, mb = 1.0f - ab + 1e-15f;
        float p = scan_incl_mul(ma * mb, lane);
        float T0 = __shfl_up(p, 1, 64);
        if (lane == 0) T0 = 1.0f;
        R.scr[2 * lane]     = aa * T0;
        R.scr[2 * lane + 1] = ab * (T0 * ma);
    }

    // --- wave-parallel CDF over pdf[m]=w[1+m]+1e-5, m=0..125 ---
    {
        float pA = 0.f, pB = 0.f;
        if (lane < 63) {
            pA = R.scr[2 * lane + 1] + 1e-5f;
            pB = R.scr[2 * lane + 2] + 1e-5f;
        }
        float S = scan_incl_add(pA + pB, lane);
        float total = __shfl(S, 63, 64);
        float sexcl = __shfl_up(S, 1, 64);
        if (lane == 0) sexcl = 0.f;
        float inv = 1.0f / total;
        if (lane == 63) {
            R.cdf[0] = 0.0f;
        } else {
            R.cdf[1 + 2 * lane] = (sexcl + pA) * inv;
            R.cdf[2 + 2 * lane] = (sexcl + pA + pB) * inv;
        }
    }

    // --- inverse-CDF sampling: i0=lane, i1=lane+64 ---
#pragma unroll
    for (int bt = 0; bt < 2; ++bt) {
        int i = bt * 64 + lane;
        float u = (float)(2 * i + 1) * (1.0f / 256.0f);
        int lo = 0, hi = 127;   // searchsorted right over cdf[0..126]
        while (lo < hi) { int mid = (lo + hi) >> 1; if (R.cdf[mid] <= u) lo = mid + 1; else hi = mid; }
        int below = max(lo - 1, 0), above = min(lo, 126);
        float cb = R.cdf[below], ca = R.cdf[above];
        float binb = fmaf(dzc, (float)below + 0.5f, nearv);
        float bina = fmaf(dzc, (float)above + 0.5f, nearv);
        float denom = ca - cb;
        if (denom < 1e-5f) denom = 1.0f;
        float t = (u - cb) / denom;
        R.zf[i] = fmaf(t, bina - binb, binb);
    }

    // --- fine eval: 2 batches, one sample per lane ---
#pragma unroll 1
    for (int bt = 0; bt < 2; ++bt) {
        int s = bt * 64 + lane;
        float z = R.zf[s];
        float px = fminf(fmaxf(fmaf(dx, z, ox), -BOUNDF), BOUNDF);
        float py = fminf(fmaxf(fmaf(dy, z, oy), -BOUNDF), BOUNDF);
        float pz = fminf(fmaxf(fmaf(dzv, z, oz), -BOUNDF), BOUNDF);
        float sg, cr, cg, cb;
        eval_field1(px, py, pz, sW1t, sW2t, base_r, base_g, base_b, sg, cr, cg, cb);
        R.sgf[s] = sg;
        R.rgbf[s][0] = cr; R.rgbf[s][1] = cg; R.rgbf[s][2] = cb;
    }

    // --- stable merge of two sorted length-128 lists (merge-path ranks) ---
#pragma unroll
    for (int bt = 0; bt < 2; ++bt) {
        int k = bt * 64 + lane;
        float v = R.zc[k];
        int lo = 0, hi = 128;
        while (lo < hi) { int mid = (lo + hi) >> 1; if (R.zf[mid] < v) lo = mid + 1; else hi = mid; }
        R.perm[k + lo] = (unsigned short)k;
        float vf = R.zf[k];
        lo = 0; hi = 128;
        while (lo < hi) { int mid = (lo + hi) >> 1; if (R.zc[mid] <= vf) lo = mid + 1; else hi = mid; }
        R.perm[k + lo] = (unsigned short)(128 + k);
    }

    // --- merged composite: 4 samples per lane, scan + accumulate in regs ---
    {
        int sb = 4 * lane;
        int idxk[4]; float zk[4], sgk[4];
#pragma unroll
        for (int k = 0; k < 4; ++k) {
            int idx = R.perm[sb + k];
            idxk[k] = idx;
            zk[k]  = (idx < 128) ? R.zc[idx]  : R.zf[idx - 128];
            sgk[k] = (idx < 128) ? R.sgc[idx] : R.sgf[idx - 128];
        }
        float znext = __shfl_down(zk[0], 1, 64);   // z of sample 4l+4
        float d0 = zk[1] - zk[0];
        float d1 = zk[2] - zk[1];
        float d2 = zk[3] - zk[2];
        float d3 = (lane < 63) ? (znext - zk[3]) : sample_dist;
        float a0 = 1.0f - __expf(-d0 * sgk[0]);
        float a1 = 1.0f - __expf(-d1 * sgk[1]);
        float a2 = 1.0f - __expf(-d2 * sgk[2]);
        float a3 = 1.0f - __expf(-d3 * sgk[3]);
        float m0 = 1.0f - a0 + 1e-15f, m1 = 1.0f - a1 + 1e-15f;
        float m2 = 1.0f - a2 + 1e-15f, m3 = 1.0f - a3 + 1e-15f;
        float p = scan_incl_mul((m0 * m1) * (m2 * m3), lane);
        float T = __shfl_up(p, 1, 64);
        if (lane == 0) T = 1.0f;

        const float invspan = 1.0f / span;  // span==0 -> inf; 0*inf = NaN (matches jnp)
        float dacc = 0.f, racc = 0.f, gacc = 0.f, bacc = 0.f, wacc = 0.f;
        float aarr[4] = {a0, a1, a2, a3};
        float marr[4] = {m0, m1, m2, m3};
#pragma unroll
        for (int k = 0; k < 4; ++k) {
            float w = aarr[k] * T;
            float ozv = (zk[k] - nearv) * invspan;
            ozv = (ozv < 0.0f) ? 0.0f : ((ozv > 1.0f) ? 1.0f : ozv);  // NaN propagates
            dacc = fmaf(w, ozv, dacc);
            const float* rgb = (idxk[k] < 128) ? R.rgbc[idxk[k]] : R.rgbf[idxk[k] - 128];
            racc = fmaf(w, rgb[0], racc);
            gacc = fmaf(w, rgb[1], gacc);
            bacc = fmaf(w, rgb[2], bacc);
            wacc += w;
            T *= marr[k];
        }
#pragma unroll
        for (int off = 32; off; off >>= 1) {
            dacc += __shfl_xor(dacc, off);
            racc += __shfl_xor(racc, off);
            gacc += __shfl_xor(gacc, off);
            bacc += __shfl_xor(bacc, off);
            wacc += __shfl_xor(wacc, off);
        }
        if (lane == 0 && valid) {
            out_depth[ray] = dacc;
            float bg = 1.0f - wacc;
            out_img[ray * 3 + 0] = racc + bg;
            out_img[ray * 3 + 1] = gacc + bg;
            out_img[ray * 3 + 2] = bacc + bg;
        }
    }
}

extern "C" void kernel_launch(void* const* d_in, const int* in_sizes, int n_in,
                              void* d_out, int out_size, void* d_ws, size_t ws_size,
                              hipStream_t stream) {
    const float* rays_o = (const float*)d_in[0];
    const float* rays_d = (const float*)d_in[1];
    const float* W1   = (const float*)d_in[2];
    const float* b1   = (const float*)d_in[3];
    const float* W2   = (const float*)d_in[4];
    const float* b2   = (const float*)d_in[5];
    const float* Wsig = (const float*)d_in[6];
    const float* Wrgb = (const float*)d_in[7];
    const float* brgb = (const float*)d_in[8];

    int N = in_sizes[0] / 3;          // 4096 rays
    float* out = (float*)d_out;
    float* out_depth = out;           // [N]
    float* out_img   = out + N;       // [N,3]

    int blocks = (N + 3) / 4;
    nerf_kernel<<<dim3(blocks), dim3(256), 0, stream>>>(
        rays_o, rays_d, W1, b1, W2, b2, Wsig, Wrgb, brgb,
        out_depth, out_img, N);
}

// Round 5
// 248.414 us; speedup vs baseline: 2.1282x; 2.1282x over previous
//
#include <hip/hip_runtime.h>
#include <math.h>

// NeRF renderer: 4096 rays, 128 coarse + 128 fine samples, tiny MLP field.
// One wave (64 lanes) per ray; TWO samples per lane in MLP evals, with layer-1
// activations packed as f16x2 (64 VGPRs for both samples) and layer-2 done via
// v_dot2_f32_f16 (fp16 mul, fp32 accumulate) against fp16 W2 rows in LDS.
//
// Lessons encoded here:
//  R2/R3: fp32 h1 for 2 samples = 128 live floats -> scratch spill (275-520 MB
//         HBM). f16x2 packing halves that to 64 regs -> fits a 128-VGPR cap.
//  R4:    fp32 LDS weight reads are the bottleneck (~4600 ds_read_b128/ray,
//         LDS-issue-bound). fp16 rows + 2-sample sharing cuts reads ~3.3x.
//  (256,2) caps VGPR at 128: good NOW because live state ~106 fits; gives
//  4 waves/SIMD, and 39 KB LDS/block gives 4 blocks/CU (grid fully resident).

#define BOUNDF 2.0f

typedef _Float16 f16;
typedef f16 f16x2 __attribute__((ext_vector_type(2)));
typedef f16 f16x8 __attribute__((ext_vector_type(8)));

struct RayLds {
    float zc[128];        // coarse z
    float zf[128];        // fine z (sorted by construction)
    float sgc[128];       // coarse sigma
    float sgf[128];       // fine sigma
    float rgbc[128][3];
    float rgbf[128][3];
    float cdf[128];       // 127 used
    float scr[128];       // alphas -> weights scratch
    unsigned short perm[256];
};

__device__ __forceinline__ float sigmoidf(float x) { return 1.0f / (1.0f + __expf(-x)); }

__device__ __forceinline__ float fdot2(f16x2 a, f16x2 b, float c) {
    return __builtin_amdgcn_fdot2(a, b, c, false);   // v_dot2_f32_f16
}

__device__ __forceinline__ float scan_incl_mul(float p, int lane) {
#pragma unroll
    for (int off = 1; off < 64; off <<= 1) {
        float t = __shfl_up(p, off, 64);
        if (lane >= off) p *= t;
    }
    return p;
}

__device__ __forceinline__ float scan_incl_add(float p, int lane) {
#pragma unroll
    for (int off = 1; off < 64; off <<= 1) {
        float t = __shfl_up(p, off, 64);
        if (lane >= off) p += t;
    }
    return p;
}

// MLP field eval for TWO points per lane (A and B). Weights in LDS:
//   sW1t[j] = {W1[0][j], W1[1][j], W1[2][j], b1[j]}           (fp32)
//   sW2h row j (stride 80 halves): [0..63] = W2[:,j] as fp16
//   sHD[j]  = {Wsig[j], Wrgb[j][0], Wrgb[j][1], Wrgb[j][2]}    (fp32)
//   sB2[j]  = b2[j]                                            (fp32)
__device__ __forceinline__ void eval_field2(
    float pxA, float pyA, float pzA, float pxB, float pyB, float pzB,
    const float4* __restrict__ sW1t, const f16* __restrict__ sW2h,
    const float4* __restrict__ sHD, const float* __restrict__ sB2,
    float base_r, float base_g, float base_b,
    float& sgA, float& rA, float& gA, float& bA,
    float& sgB, float& rB, float& gB, float& bB)
{
    // layer 1 (fp32 compute, packed f16x2 store: pair (2j, 2j+1))
    f16x2 h1a[32], h1b[32];
#pragma unroll
    for (int j = 0; j < 32; ++j) {
        float4 w0 = sW1t[2 * j], w1 = sW1t[2 * j + 1];
        float vA0 = fmaxf(fmaf(pxA, w0.x, fmaf(pyA, w0.y, fmaf(pzA, w0.z, w0.w))), 0.0f);
        float vA1 = fmaxf(fmaf(pxA, w1.x, fmaf(pyA, w1.y, fmaf(pzA, w1.z, w1.w))), 0.0f);
        float vB0 = fmaxf(fmaf(pxB, w0.x, fmaf(pyB, w0.y, fmaf(pzB, w0.z, w0.w))), 0.0f);
        float vB1 = fmaxf(fmaf(pxB, w1.x, fmaf(pyB, w1.y, fmaf(pzB, w1.z, w1.w))), 0.0f);
        h1a[j] = f16x2{(f16)vA0, (f16)vA1};
        h1b[j] = f16x2{(f16)vB0, (f16)vB1};
    }

    float asA = 0.f, c0A = 0.f, c1A = 0.f, c2A = 0.f;
    float asB = 0.f, c0B = 0.f, c1B = 0.f, c2B = 0.f;
#pragma unroll 2
    for (int j = 0; j < 64; ++j) {
        const f16* row = sW2h + j * 80;
        float b2j = sB2[j];
        float aA0 = b2j, aA1 = 0.f, aB0 = b2j, aB1 = 0.f;  // 2 chains/sample
#pragma unroll
        for (int i = 0; i < 8; ++i) {
            f16x8 w = *(const f16x8*)(row + i * 8);        // 16B broadcast read
            f16x2 w0 = f16x2{w[0], w[1]};
            f16x2 w1 = f16x2{w[2], w[3]};
            f16x2 w2 = f16x2{w[4], w[5]};
            f16x2 w3 = f16x2{w[6], w[7]};
            aA0 = fdot2(h1a[4 * i + 0], w0, aA0);
            aA1 = fdot2(h1a[4 * i + 1], w1, aA1);
            aA0 = fdot2(h1a[4 * i + 2], w2, aA0);
            aA1 = fdot2(h1a[4 * i + 3], w3, aA1);
            aB0 = fdot2(h1b[4 * i + 0], w0, aB0);
            aB1 = fdot2(h1b[4 * i + 1], w1, aB1);
            aB0 = fdot2(h1b[4 * i + 2], w2, aB0);
            aB1 = fdot2(h1b[4 * i + 3], w3, aB1);
        }
        float h2A = fmaxf(aA0 + aA1, 0.0f);
        float h2B = fmaxf(aB0 + aB1, 0.0f);
        float4 hd = sHD[j];   // Wsig, Wrgb0, Wrgb1, Wrgb2
        asA = fmaf(h2A, hd.x, asA); c0A = fmaf(h2A, hd.y, c0A);
        c1A = fmaf(h2A, hd.z, c1A); c2A = fmaf(h2A, hd.w, c2A);
        asB = fmaf(h2B, hd.x, asB); c0B = fmaf(h2B, hd.y, c0B);
        c1B = fmaf(h2B, hd.z, c1B); c2B = fmaf(h2B, hd.w, c2B);
    }
    sgA = fmaxf(asA, 0.0f) + log1pf(__expf(-fabsf(asA)));   // stable softplus
    sgB = fmaxf(asB, 0.0f) + log1pf(__expf(-fabsf(asB)));
    rA = sigmoidf(c0A + base_r); gA = sigmoidf(c1A + base_g); bA = sigmoidf(c2A + base_b);
    rB = sigmoidf(c0B + base_r); gB = sigmoidf(c1B + base_g); bB = sigmoidf(c2B + base_b);
}

__global__ __launch_bounds__(256, 2)
void nerf_kernel(const float* __restrict__ rays_o, const float* __restrict__ rays_d,
                 const float* __restrict__ W1, const float* __restrict__ b1,
                 const float* __restrict__ W2, const float* __restrict__ b2,
                 const float* __restrict__ Wsig, const float* __restrict__ Wrgb,
                 const float* __restrict__ brgb,
                 float* __restrict__ out_depth, float* __restrict__ out_img,
                 int nRays)
{
    __shared__ __align__(16) float4 sW1t[64];
    __shared__ __align__(16) f16 sW2h[64 * 80];
    __shared__ __align__(16) float4 sHD[64];
    __shared__ float sB2[64];
    __shared__ RayLds rl[4];

    const int tid  = threadIdx.x;
    const int lane = tid & 63;
    const int wv   = tid >> 6;

    // --- stage weights (whole block) ---
    if (tid < 64) {
        sW1t[tid] = make_float4(W1[tid], W1[64 + tid], W1[128 + tid], b1[tid]);
        sHD[tid]  = make_float4(Wsig[tid], Wrgb[tid * 3 + 0], Wrgb[tid * 3 + 1], Wrgb[tid * 3 + 2]);
        sB2[tid]  = b2[tid];
    }
    for (int idx = tid; idx < 4096; idx += 256) {
        int i = idx >> 6, j = idx & 63;
        sW2h[j * 80 + i] = (f16)W2[i * 64 + j];   // transposed, fp16
    }
    __syncthreads();

    int ray = blockIdx.x * 4 + wv;
    bool valid = ray < nRays;
    int rayc = valid ? ray : (nRays - 1);
    RayLds& R = rl[wv];

    const float ox = rays_o[rayc * 3 + 0], oy = rays_o[rayc * 3 + 1], oz = rays_o[rayc * 3 + 2];
    const float dx = rays_d[rayc * 3 + 0], dy = rays_d[rayc * 3 + 1], dzv = rays_d[rayc * 3 + 2];

    // --- near/far vs cube [-2,2]^3 ---
    float t0x = (-BOUNDF - ox) / (dx + 1e-15f), t1x = (BOUNDF - ox) / (dx + 1e-15f);
    float t0y = (-BOUNDF - oy) / (dy + 1e-15f), t1y = (BOUNDF - oy) / (dy + 1e-15f);
    float t0z = (-BOUNDF - oz) / (dzv + 1e-15f), t1z = (BOUNDF - oz) / (dzv + 1e-15f);
    float nearv = fmaxf(fminf(t0x, t1x), fmaxf(fminf(t0y, t1y), fminf(t0z, t1z)));
    float farv  = fminf(fmaxf(t0x, t1x), fminf(fmaxf(t0y, t1y), fmaxf(t0z, t1z)));
    if (farv < nearv) { nearv = 1e9f; farv = 1e9f; }
    nearv = fmaxf(nearv, 0.05f);
    const float span = farv - nearv;
    const float dzc = span * (1.0f / 127.0f);
    const float sample_dist = span * (1.0f / 128.0f);

    // per-ray rgb bias: brgb + dirs @ Wrgb[64:67]
    const float base_r = brgb[0] + dx * Wrgb[64 * 3 + 0] + dy * Wrgb[65 * 3 + 0] + dzv * Wrgb[66 * 3 + 0];
    const float base_g = brgb[1] + dx * Wrgb[64 * 3 + 1] + dy * Wrgb[65 * 3 + 1] + dzv * Wrgb[66 * 3 + 1];
    const float base_b = brgb[2] + dx * Wrgb[64 * 3 + 2] + dy * Wrgb[65 * 3 + 2] + dzv * Wrgb[66 * 3 + 2];

    const int s0 = lane, s1 = lane + 64;

    // --- coarse eval: samples s0 (A) and s1 (B) per lane ---
    {
        float zA = fmaf(span, (float)s0 * (1.0f / 127.0f), nearv);
        float zB = fmaf(span, (float)s1 * (1.0f / 127.0f), nearv);
        R.zc[s0] = zA; R.zc[s1] = zB;
        float pxA = fminf(fmaxf(fmaf(dx, zA, ox), -BOUNDF), BOUNDF);
        float pyA = fminf(fmaxf(fmaf(dy, zA, oy), -BOUNDF), BOUNDF);
        float pzA = fminf(fmaxf(fmaf(dzv, zA, oz), -BOUNDF), BOUNDF);
        float pxB = fminf(fmaxf(fmaf(dx, zB, ox), -BOUNDF), BOUNDF);
        float pyB = fminf(fmaxf(fmaf(dy, zB, oy), -BOUNDF), BOUNDF);
        float pzB = fminf(fmaxf(fmaf(dzv, zB, oz), -BOUNDF), BOUNDF);
        float sgA, rA, gA, bA, sgB, rB, gB, bB;
        eval_field2(pxA, pyA, pzA, pxB, pyB, pzB, sW1t, sW2h, sHD, sB2,
                    base_r, base_g, base_b, sgA, rA, gA, bA, sgB, rB, gB, bB);
        R.sgc[s0] = sgA; R.rgbc[s0][0] = rA; R.rgbc[s0][1] = gA; R.rgbc[s0][2] = bA;
        R.sgc[s1] = sgB; R.rgbc[s1][0] = rB; R.rgbc[s1][1] = gB; R.rgbc[s1][2] = bB;

        // coarse alphas (deltas from actual z, matching reference)
        float znA = R.zc[s0 + 1];
        int   snB = (s1 < 127) ? s1 + 1 : 127;
        float znB = R.zc[snB];
        float dA = znA - zA;
        float dB = (s1 < 127) ? (znB - zB) : sample_dist;
        R.scr[s0] = 1.0f - __expf(-dA * sgA);
        R.scr[s1] = 1.0f - __expf(-dB * sgB);
    }

    // --- wave-parallel cumprod: weights for elements 2l, 2l+1 ---
    {
        float aa = R.scr[2 * lane], ab = R.scr[2 * lane + 1];
        float ma = 1.0f - aa + 1e-15f, mb = 1.0f - ab + 1e-15f;
        float p = scan_incl_mul(ma * mb, lane);
        float T0 = __shfl_up(p, 1, 64);
        if (lane == 0) T0 = 1.0f;
        R.scr[2 * lane]     = aa * T0;
        R.scr[2 * lane + 1] = ab * (T0 * ma);
    }

    // --- wave-parallel CDF over pdf[m]=w[1+m]+1e-5, m=0..125 ---
    {
        float pA = 0.f, pB = 0.f;
        if (lane < 63) {
            pA = R.scr[2 * lane + 1] + 1e-5f;
            pB = R.scr[2 * lane + 2] + 1e-5f;
        }
        float S = scan_incl_add(pA + pB, lane);
        float total = __shfl(S, 63, 64);
        float sexcl = __shfl_up(S, 1, 64);
        if (lane == 0) sexcl = 0.f;
        float inv = 1.0f / total;
        if (lane == 63) {
            R.cdf[0] = 0.0f;
        } else {
            R.cdf[1 + 2 * lane] = (sexcl + pA) * inv;
            R.cdf[2 + 2 * lane] = (sexcl + pA + pB) * inv;
        }
    }

    // --- inverse-CDF sampling: i0=lane, i1=lane+64 ---
#pragma unroll
    for (int bt = 0; bt < 2; ++bt) {
        int i = bt * 64 + lane;
        float u = (float)(2 * i + 1) * (1.0f / 256.0f);
        int lo = 0, hi = 127;   // searchsorted right over cdf[0..126]
        while (lo < hi) { int mid = (lo + hi) >> 1; if (R.cdf[mid] <= u) lo = mid + 1; else hi = mid; }
        int below = max(lo - 1, 0), above = min(lo, 126);
        float cb = R.cdf[below], ca = R.cdf[above];
        float binb = fmaf(dzc, (float)below + 0.5f, nearv);
        float bina = fmaf(dzc, (float)above + 0.5f, nearv);
        float denom = ca - cb;
        if (denom < 1e-5f) denom = 1.0f;
        float t = (u - cb) / denom;
        R.zf[i] = fmaf(t, bina - binb, binb);
    }

    // --- fine eval: samples s0 (A) and s1 (B) per lane ---
    {
        float zA = R.zf[s0], zB = R.zf[s1];
        float pxA = fminf(fmaxf(fmaf(dx, zA, ox), -BOUNDF), BOUNDF);
        float pyA = fminf(fmaxf(fmaf(dy, zA, oy), -BOUNDF), BOUNDF);
        float pzA = fminf(fmaxf(fmaf(dzv, zA, oz), -BOUNDF), BOUNDF);
        float pxB = fminf(fmaxf(fmaf(dx, zB, ox), -BOUNDF), BOUNDF);
        float pyB = fminf(fmaxf(fmaf(dy, zB, oy), -BOUNDF), BOUNDF);
        float pzB = fminf(fmaxf(fmaf(dzv, zB, oz), -BOUNDF), BOUNDF);
        float sgA, rA, gA, bA, sgB, rB, gB, bB;
        eval_field2(pxA, pyA, pzA, pxB, pyB, pzB, sW1t, sW2h, sHD, sB2,
                    base_r, base_g, base_b, sgA, rA, gA, bA, sgB, rB, gB, bB);
        R.sgf[s0] = sgA; R.rgbf[s0][0] = rA; R.rgbf[s0][1] = gA; R.rgbf[s0][2] = bA;
        R.sgf[s1] = sgB; R.rgbf[s1][0] = rB; R.rgbf[s1][1] = gB; R.rgbf[s1][2] = bB;
    }

    // --- stable merge of two sorted length-128 lists (merge-path ranks) ---
#pragma unroll
    for (int bt = 0; bt < 2; ++bt) {
        int k = bt * 64 + lane;
        float v = R.zc[k];
        int lo = 0, hi = 128;
        while (lo < hi) { int mid = (lo + hi) >> 1; if (R.zf[mid] < v) lo = mid + 1; else hi = mid; }
        R.perm[k + lo] = (unsigned short)k;
        float vf = R.zf[k];
        lo = 0; hi = 128;
        while (lo < hi) { int mid = (lo + hi) >> 1; if (R.zc[mid] <= vf) lo = mid + 1; else hi = mid; }
        R.perm[k + lo] = (unsigned short)(128 + k);
    }

    // --- merged composite: 4 samples per lane, scan + accumulate in regs ---
    {
        int sb = 4 * lane;
        int idxk[4]; float zk[4], sgk[4];
#pragma unroll
        for (int k = 0; k < 4; ++k) {
            int idx = R.perm[sb + k];
            idxk[k] = idx;
            zk[k]  = (idx < 128) ? R.zc[idx]  : R.zf[idx - 128];
            sgk[k] = (idx < 128) ? R.sgc[idx] : R.sgf[idx - 128];
        }
        float znext = __shfl_down(zk[0], 1, 64);   // z of sample 4l+4
        float d0 = zk[1] - zk[0];
        float d1 = zk[2] - zk[1];
        float d2 = zk[3] - zk[2];
        float d3 = (lane < 63) ? (znext - zk[3]) : sample_dist;
        float a0 = 1.0f - __expf(-d0 * sgk[0]);
        float a1 = 1.0f - __expf(-d1 * sgk[1]);
        float a2 = 1.0f - __expf(-d2 * sgk[2]);
        float a3 = 1.0f - __expf(-d3 * sgk[3]);
        float m0 = 1.0f - a0 + 1e-15f, m1 = 1.0f - a1 + 1e-15f;
        float m2 = 1.0f - a2 + 1e-15f, m3 = 1.0f - a3 + 1e-15f;
        float p = scan_incl_mul((m0 * m1) * (m2 * m3), lane);
        float T = __shfl_up(p, 1, 64);
        if (lane == 0) T = 1.0f;

        const float invspan = 1.0f / span;  // span==0 -> inf; 0*inf = NaN (matches jnp)
        float dacc = 0.f, racc = 0.f, gacc = 0.f, bacc = 0.f, wacc = 0.f;
        float aarr[4] = {a0, a1, a2, a3};
        float marr[4] = {m0, m1, m2, m3};
#pragma unroll
        for (int k = 0; k < 4; ++k) {
            float w = aarr[k] * T;
            float ozv = (zk[k] - nearv) * invspan;
            ozv = (ozv < 0.0f) ? 0.0f : ((ozv > 1.0f) ? 1.0f : ozv);  // NaN propagates
            dacc = fmaf(w, ozv, dacc);
            const float* rgb = (idxk[k] < 128) ? R.rgbc[idxk[k]] : R.rgbf[idxk[k] - 128];
            racc = fmaf(w, rgb[0], racc);
            gacc = fmaf(w, rgb[1], gacc);
            bacc = fmaf(w, rgb[2], bacc);
            wacc += w;
            T *= marr[k];
        }
#pragma unroll
        for (int off = 32; off; off >>= 1) {
            dacc += __shfl_xor(dacc, off);
            racc += __shfl_xor(racc, off);
            gacc += __shfl_xor(gacc, off);
            bacc += __shfl_xor(bacc, off);
            wacc += __shfl_xor(wacc, off);
        }
        if (lane == 0 && valid) {
            out_depth[ray] = dacc;
            float bg = 1.0f - wacc;
            out_img[ray * 3 + 0] = racc + bg;
            out_img[ray * 3 + 1] = gacc + bg;
            out_img[ray * 3 + 2] = bacc + bg;
        }
    }
}

extern "C" void kernel_launch(void* const* d_in, const int* in_sizes, int n_in,
                              void* d_out, int out_size, void* d_ws, size_t ws_size,
                              hipStream_t stream) {
    const float* rays_o = (const float*)d_in[0];
    const float* rays_d = (const float*)d_in[1];
    const float* W1   = (const float*)d_in[2];
    const float* b1   = (const float*)d_in[3];
    const float* W2   = (const float*)d_in[4];
    const float* b2   = (const float*)d_in[5];
    const float* Wsig = (const float*)d_in[6];
    const float* Wrgb = (const float*)d_in[7];
    const float* brgb = (const float*)d_in[8];

    int N = in_sizes[0] / 3;          // 4096 rays
    float* out = (float*)d_out;
    float* out_depth = out;           // [N]
    float* out_img   = out + N;       // [N,3]

    int blocks = (N + 3) / 4;
    nerf_kernel<<<dim3(blocks), dim3(256), 0, stream>>>(
        rays_o, rays_d, W1, b1, W2, b2, Wsig, Wrgb, brgb,
        out_depth, out_img, N);
}